// Round 4
// baseline (763.467 us; speedup 1.0000x reference)
//
#include <hip/hip_runtime.h>
#include <math.h>

// Problem constants (from reference): B=16384, N=64, D=64
#define BATCH 16384
#define NN 64
#define DD 64
#define RS 65   // stride 65: bank = (n + k) % 32 -> 2-way on b32 reads = free (m136)

// 4 waves per block, one batch per block. Wave w computes j in [16w,16w+16)
// for all 64 neighbors (lane = neighbor). W1b is held LANE-RESIDENT:
// wreg[jj] = W1b[lane][16w+jj]; the k-loop broadcasts it with v_readlane
// (pure VALU) -> no s_load / lgkmcnt-drain / K$ bandwidth in the hot loop.
// VGPR ~60 (wreg16 + acc16 + nvr16) -> __launch_bounds__(256,6) (cap 85).
__global__ __launch_bounds__(256, 6)
void aggregator_kernel(const float* __restrict__ self_v,   // [B,1,64]
                       const float* __restrict__ nv,       // [B,1,64,64]
                       const float* __restrict__ rel,      // [B,1,64,64]
                       const float* __restrict__ ue,       // [B,64]
                       const float* __restrict__ W1,       // [128,64]
                       const float* __restrict__ b1,       // [64]
                       const float* __restrict__ w2,       // [64,1]
                       const float* __restrict__ b2,       // [1]
                       float* __restrict__ out)            // [B,1,128]
{
    const int b = blockIdx.x;
    const int t = threadIdx.x;                              // 0..255
    const int lane = t & 63;
    const int w = __builtin_amdgcn_readfirstlane(t >> 6);   // wave id 0..3 (SGPR)

    __shared__ float rel_s[NN * RS];    // 16640 B
    __shared__ float u1p_s[4][DD];      // u1 k-quarter partials
    __shared__ float pd_s[4][DD];       // w2-dot j-quarter partials
    __shared__ float agg_s[4][DD];      // aggregation n-quarter partials
    // total 19712 B -> LDS allows 8 blocks/CU

    const float* __restrict__ relb = rel + (size_t)b * (NN * DD);

    // ---- 1. issue rel tile loads (cold HBM, deepest latency first) ----
    float4 r[4];
    #pragma unroll
    for (int i = 0; i < 4; ++i) r[i] = ((const float4*)relb)[i * 256 + t];

    // ---- 2. gather lane-resident W1b slice: wreg[jj] = W1b[lane][16w+jj] ----
    // One 64B line per lane (L2/L3-hot; same lines for every block).
    float wreg[16];
    {
        const float* __restrict__ wrow = W1 + DD * DD + lane * DD + 16 * w;
        float4 q0 = *(const float4*)(wrow + 0);
        float4 q1 = *(const float4*)(wrow + 4);
        float4 q2 = *(const float4*)(wrow + 8);
        float4 q3 = *(const float4*)(wrow + 12);
        wreg[0]=q0.x;  wreg[1]=q0.y;  wreg[2]=q0.z;  wreg[3]=q0.w;
        wreg[4]=q1.x;  wreg[5]=q1.y;  wreg[6]=q1.z;  wreg[7]=q1.w;
        wreg[8]=q2.x;  wreg[9]=q2.y;  wreg[10]=q2.z; wreg[11]=q2.w;
        wreg[12]=q3.x; wreg[13]=q3.y; wreg[14]=q3.z; wreg[15]=q3.w;
    }

    // ---- 3. issue nv prefetch NOW; pin with sched_barrier so it can't sink ----
    // wave w covers n in [16w,16w+16), j = lane (coalesced 256B rows)
    const float* __restrict__ nvb = nv + (size_t)b * (NN * DD) + (size_t)(16 * w) * DD + lane;
    float nvr[16];
    #pragma unroll
    for (int i = 0; i < 16; ++i) nvr[i] = nvb[(size_t)i * DD];
    __builtin_amdgcn_sched_barrier(0);   // loads stay issued here (defeat sinking)

    // ---- 4. u1 partial: thread covers j=lane, k in [16w,16w+16) ----
    {
        const float* __restrict__ ueb = ue + (size_t)b * DD + 16 * w;  // uniform -> s_load
        float pu = 0.0f;
        #pragma unroll
        for (int kk = 0; kk < 16; ++kk) {
            pu = fmaf(ueb[kk], W1[(16 * w + kk) * DD + lane], pu);     // W1a coalesced
        }
        u1p_s[w][lane] = pu;
    }

    // self-vector passthrough: only wave 0 needs it
    float sv = 0.0f;
    if (w == 0) sv = self_v[(size_t)b * DD + lane];

    // ---- 5. write rel to LDS (vmcnt wait lands here), stride-65 rows ----
    #pragma unroll
    for (int i = 0; i < 4; ++i) {
        int idx = i * 256 + t;                 // float4 index within 64x64 tile
        int n = idx >> 4;                      // row (neighbor)
        int k = (idx & 15) * 4;                // col
        float* p = &rel_s[n * RS + k];
        p[0] = r[i].x; p[1] = r[i].y; p[2] = r[i].z; p[3] = r[i].w;
    }
    __syncthreads();   // sync1: rel_s + u1p_s ready

    // ---- 6. acc init: u1[16w+jj] = b1 + 4 partials (float4 uniform reads) ----
    float acc[16];
    #pragma unroll
    for (int q = 0; q < 4; ++q) {
        float4 a = *(const float4*)(b1 + 16 * w + 4 * q);   // uniform -> s_load
        #pragma unroll
        for (int p = 0; p < 4; ++p) {
            float4 u = *(const float4*)&u1p_s[p][16 * w + 4 * q];  // uniform b128 broadcast
            a.x += u.x; a.y += u.y; a.z += u.z; a.w += u.w;
        }
        acc[4*q+0] = a.x; acc[4*q+1] = a.y; acc[4*q+2] = a.z; acc[4*q+3] = a.w;
    }

    // ---- 7. main loop: register+LDS only; W broadcast via v_readlane ----
    #pragma unroll 8
    for (int k = 0; k < DD; ++k) {
        float x = rel_s[lane * RS + k];        // bank=(lane+k)&31: 2-way, free
        #pragma unroll
        for (int jj = 0; jj < 16; ++jj) {
            float wk = __int_as_float(
                __builtin_amdgcn_readlane(__float_as_int(wreg[jj]), k));
            acc[jj] = fmaf(x, wk, acc[jj]);
        }
    }

    // ---- 8. partial dot with w2 over this j-quarter ----
    {
        const float* __restrict__ w2q = w2 + 16 * w;        // uniform -> s_load
        float pd = 0.0f;
        #pragma unroll
        for (int jj = 0; jj < 16; ++jj) pd = fmaf(fmaxf(acc[jj], 0.0f), w2q[jj], pd);
        pd_s[w][lane] = pd;
    }
    __syncthreads();   // sync2: pd partials ready

    // ---- 9. decay + softmax over 64 neighbors (redundant per wave; n = lane) ----
    float d = b2[0] + pd_s[0][lane] + pd_s[1][lane] + pd_s[2][lane] + pd_s[3][lane];
    float dec = 1.0f / (1.0f + __expf(-d));
    float m = dec;
    #pragma unroll
    for (int off = 32; off > 0; off >>= 1) m = fmaxf(m, __shfl_xor(m, off, 64));
    float e = __expf(dec - m);
    float s = e;
    #pragma unroll
    for (int off = 32; off > 0; off >>= 1) s += __shfl_xor(s, off, 64);
    float wv = e / s;                  // softmax weight for neighbor 'lane'

    // ---- 10. aggregation from prefetched registers ----
    float pa = 0.0f;
    #pragma unroll
    for (int i = 0; i < 16; ++i) {
        float wi = __int_as_float(
            __builtin_amdgcn_readlane(__float_as_int(wv), 16 * w + i));
        pa = fmaf(wi, nvr[i], pa);
    }
    agg_s[w][lane] = pa;

    // self half of the output can go out before the last barrier
    if (w == 0) out[(size_t)b * (2 * DD) + lane] = sv;
    __syncthreads();   // sync3: agg partials ready

    if (w == 0) {
        out[(size_t)b * (2 * DD) + DD + lane] =
            agg_s[0][lane] + agg_s[1][lane] + agg_s[2][lane] + agg_s[3][lane];
    }
}

extern "C" void kernel_launch(void* const* d_in, const int* in_sizes, int n_in,
                              void* d_out, int out_size, void* d_ws, size_t ws_size,
                              hipStream_t stream) {
    const float* self_v = (const float*)d_in[0];
    const float* nv     = (const float*)d_in[1];
    const float* rel    = (const float*)d_in[2];
    const float* ue     = (const float*)d_in[3];
    const float* W1     = (const float*)d_in[4];
    const float* b1     = (const float*)d_in[5];
    const float* w2     = (const float*)d_in[6];
    const float* b2     = (const float*)d_in[7];
    float* out = (float*)d_out;

    aggregator_kernel<<<dim3(BATCH), dim3(256), 0, stream>>>(
        self_v, nv, rel, ue, W1, b1, w2, b2, out);
}